// Round 13
// baseline (496.946 us; speedup 1.0000x reference)
//
#include <hip/hip_runtime.h>
#include <math.h>

#define N_NODES 100000
#define N_EDGES 1600000
#define PAD_DEG 64

typedef __bf16 bf16_t;
typedef __attribute__((ext_vector_type(8))) __bf16 bf16x8;
typedef __attribute__((ext_vector_type(4))) __bf16 bf16x4;
typedef __attribute__((ext_vector_type(4))) float f32x4;

#define GT_WHH  0
#define GT_WIH  12
#define GT_LSTM 24
#define GT_LIN  36
#define N_GT    40
#define PACK_ELEMS (N_GT * 1024)
#define CAST_BLOCKS ((N_NODES * 16 + 16 + 255) / 256)   // 6251
#define PACK_BLOCKS ((PACK_ELEMS + 255) / 256)          // 160

// edge partition: 8 dst-ranges of 12500 nodes; compact per-range buckets
#define NODES_PER_RANGE 12500
#define BUCKET_CAP 204800            // 200k mean + 11.5 sigma
#define EPB 2048                     // edges per partition block
#define PART_BLOCKS ((N_EDGES + EPB - 1) / EPB)   // 782
#define SCAT_GROUP 256               // blocks per range in k_scat

__device__ __forceinline__ float sigm(float v) { return 1.f / (1.f + __expf(-v)); }
__device__ __forceinline__ float tanh_(float v) { return 2.f * sigm(2.f * v) - 1.f; }

__device__ __forceinline__ void split8(const float* __restrict__ p, bf16x8& hi, bf16x8& lo) {
    f32x4 a = *(const f32x4*)p;
    f32x4 b = *(const f32x4*)(p + 4);
#pragma unroll
    for (int i = 0; i < 4; ++i) {
        float v = a[i];
        __bf16 h = (__bf16)v;
        hi[i] = h;
        lo[i] = (__bf16)(v - (float)h);
        v = b[i];
        h = (__bf16)v;
        hi[4 + i] = h;
        lo[4 + i] = (__bf16)(v - (float)h);
    }
}

__device__ __forceinline__ bf16x8 zero8() {
    bf16x8 r;
#pragma unroll
    for (int i = 0; i < 8; ++i) r[i] = (__bf16)0.f;
    return r;
}

__device__ __forceinline__ f32x4 mm6(f32x4 acc, bf16x8 ah0, bf16x8 ah1, bf16x8 al0, bf16x8 al1,
                                     const bf16_t* __restrict__ ph, const bf16_t* __restrict__ pl,
                                     int gt, int l) {
    const bf16x8 bh0 = *(const bf16x8*)(ph + (gt * 2 + 0) * 512 + l * 8);
    const bf16x8 bh1 = *(const bf16x8*)(ph + (gt * 2 + 1) * 512 + l * 8);
    const bf16x8 bl0 = *(const bf16x8*)(pl + (gt * 2 + 0) * 512 + l * 8);
    const bf16x8 bl1 = *(const bf16x8*)(pl + (gt * 2 + 1) * 512 + l * 8);
    acc = __builtin_amdgcn_mfma_f32_16x16x32_bf16(ah0, bh0, acc, 0, 0, 0);
    acc = __builtin_amdgcn_mfma_f32_16x16x32_bf16(ah1, bh1, acc, 0, 0, 0);
    acc = __builtin_amdgcn_mfma_f32_16x16x32_bf16(al0, bh0, acc, 0, 0, 0);
    acc = __builtin_amdgcn_mfma_f32_16x16x32_bf16(al1, bh1, acc, 0, 0, 0);
    acc = __builtin_amdgcn_mfma_f32_16x16x32_bf16(ah0, bl0, acc, 0, 0, 0);
    acc = __builtin_amdgcn_mfma_f32_16x16x32_bf16(ah1, bl1, acc, 0, 0, 0);
    return acc;
}

// ---------------- k_part: LDS-binned edge partition (+cast, +pack in same grid) ----------------
__global__ __launch_bounds__(256) void k_part(const int* __restrict__ ei,
                                              int* __restrict__ gcur, int* __restrict__ gbuf,
                                              const float* __restrict__ x, bf16_t* __restrict__ xb,
                                              const float* __restrict__ Wc,
                                              const float* __restrict__ wih,
                                              const float* __restrict__ whh,
                                              const float* __restrict__ lw,
                                              const float* __restrict__ lin,
                                              bf16_t* __restrict__ ph, bf16_t* __restrict__ pl) {
    int b = blockIdx.x;
    if (b < PART_BLOCKS) {
        __shared__ int lbuf[8][320];
        __shared__ int lcnt[8];
        int tid = threadIdx.x, lane = tid & 63, wv = tid >> 6;
        if (tid < 8) lcnt[tid] = 0;
        __syncthreads();
        int e0 = b * EPB;
        int e1 = e0 + EPB;
        if (e1 > N_EDGES) e1 = N_EDGES;
        for (int ebase = e0; ebase < e1; ebase += 256) {
            int e = ebase + tid;
            if (e < e1) {
                int d = ei[N_EDGES + e];
                int s = ei[e];
                unsigned bkt = ((unsigned)((unsigned)d * 42950u)) >> 29;   // d / 12500
                int idx = atomicAdd(&lcnt[bkt], 1);
                lbuf[bkt][idx] = (s << 14) | (d - (int)bkt * NODES_PER_RANGE);
            }
            __syncthreads();
            // wave wv flushes buckets wv and wv+4 in 64-entry coalesced chunks
#pragma unroll
            for (int bb = 0; bb < 2; ++bb) {
                int bkt = wv + bb * 4;
                int c = lcnt[bkt];
                int nf = c & ~63;
                if (nf > 0) {
                    int gb = 0;
                    if (lane == 0) gb = atomicAdd(&gcur[bkt], nf);
                    gb = __shfl(gb, 0, 64);
                    for (int i = lane; i < nf; i += 64)
                        gbuf[(size_t)bkt * BUCKET_CAP + gb + i] = lbuf[bkt][i];
                    int rem = c - nf;
                    int tmp = 0;
                    if (lane < rem) tmp = lbuf[bkt][nf + lane];
                    if (lane < rem) lbuf[bkt][lane] = tmp;
                    if (lane == 0) lcnt[bkt] = rem;
                }
            }
            __syncthreads();
        }
        // final flush (<64 each)
#pragma unroll
        for (int bb = 0; bb < 2; ++bb) {
            int bkt = wv + bb * 4;
            int c = lcnt[bkt];
            if (c > 0) {
                int gb = 0;
                if (lane == 0) gb = atomicAdd(&gcur[bkt], c);
                gb = __shfl(gb, 0, 64);
                if (lane < c)
                    gbuf[(size_t)bkt * BUCKET_CAP + gb + lane] = lbuf[bkt][lane];
            }
        }
        return;
    }
    b -= PART_BLOCKS;
    if (b < CAST_BLOCKS) {
        int t = b * 256 + threadIdx.x;
        if (t < N_NODES * 16) {
            f32x4 v = *(const f32x4*)(x + (size_t)t * 4);
            bf16x4 o;
#pragma unroll
            for (int i = 0; i < 4; ++i) o[i] = (__bf16)v[i];
            *(bf16x4*)(xb + (size_t)t * 4) = o;
        } else if (t < N_NODES * 16 + 16) {
            bf16x4 o;
#pragma unroll
            for (int i = 0; i < 4; ++i) o[i] = (__bf16)0.f;
            *(bf16x4*)(xb + (size_t)t * 4) = o;
        }
        return;
    }
    b -= CAST_BLOCKS;
    int t = b * 256 + threadIdx.x;
    if (t >= PACK_ELEMS) return;
    int i = t & 7, lane = (t >> 3) & 63, kk = (t >> 9) & 1, gt = t >> 10;
    int f = lane & 15;
    int k = kk * 32 + (lane >> 4) * 8 + i;
    float v;
    if (gt < 12) {
        v = whh[(gt * 16 + f) * 64 + k];
    } else if (gt < 24) {
        int j = (gt - 12) * 16 + f;
        float acc = 0.f;
        for (int c = 0; c < 64; ++c) acc += Wc[k * 64 + c] * wih[j * 64 + c];
        v = acc;
    } else if (gt < 36) {
        int jg = (gt - 24) * 16 + f;
        int row = (jg < 64) ? jg : jg + 64;
        v = lw[row * 64 + k];
    } else {
        v = lin[((gt - 36) * 16 + f) * 64 + k];
    }
    __bf16 h = (__bf16)v;
    ph[t] = h;
    pl[t] = (__bf16)(v - (float)h);
}

// ---------------- k_scat: range-local scatter from compact buckets ----------------
__global__ __launch_bounds__(256) void k_scat(const int* __restrict__ gbuf,
                                              const int* __restrict__ gcur,
                                              int* __restrict__ cnt, int* __restrict__ ss) {
    int r = blockIdx.x & 7, gi = blockIdx.x >> 3;   // r -> XCD under %8 round-robin
    int n = gcur[r];
    if (n > BUCKET_CAP) n = BUCKET_CAP;
    int base = r * NODES_PER_RANGE;
    const int* gb = gbuf + (size_t)r * BUCKET_CAP;
    for (int i = gi * 256 + threadIdx.x; i < n; i += SCAT_GROUP * 256) {
        int v = gb[i];
        int d = base + (v & 0x3FFF);
        int s = v >> 14;
        int p = atomicAdd(&cnt[d], 1);
        if (p < PAD_DEG) ss[d * PAD_DEG + p] = s;
    }
}

// ---------------- fused gather-mean -> (agg@WC, x@Whh) GRU -> LSTM -> ReLU+Linear ----------------
__global__ __launch_bounds__(256) void k_fused(
    const float* __restrict__ x, const bf16_t* __restrict__ xb,
    const int* __restrict__ ss, const int* __restrict__ cnt,
    const bf16_t* __restrict__ ph, const bf16_t* __restrict__ pl,
    const float* __restrict__ b_ih, const float* __restrict__ b_hh,
    const float* __restrict__ lb_ih, const float* __restrict__ lb_hh,
    const float* __restrict__ lin_b, float* __restrict__ out) {
    __shared__ float sc[4 * 16 * 68];
    int tid = threadIdx.x, w = tid >> 6, l = tid & 63;
    int base = blockIdx.x * 64 + w * 16;
    float* sw = &sc[w * 16 * 68];
    int f16 = l & 15, k0 = (l >> 4) * 8, hq = l >> 4;

    int g = l >> 4;
    int f4 = (l & 15) * 4;
    int dcl = 0;
    if (l < 16 && base + l < N_NODES) dcl = cnt[base + l];
    if (dcl > PAD_DEG) dcl = PAD_DEG;

    int idxq = 0;
    if (base < N_NODES) idxq = ss[(size_t)base * PAD_DEG + l];

#pragma unroll 1
    for (int t = 0; t < 16; ++t) {
        int dc = __shfl(dcl, t, 64);
        int idxv = (l < dc) ? idxq : N_NODES;
        if (t < 15 && base + t + 1 < N_NODES) idxq = ss[(size_t)(base + t + 1) * PAD_DEG + l];
        float a0 = 0.f, a1 = 0.f, a2 = 0.f, a3 = 0.f;

#define GLD(name, sb) \
        int s##name = __shfl(idxv, (sb) + g, 64); \
        bf16x4 v##name = *(const bf16x4*)(xb + (size_t)s##name * 64 + f4);
#define GACC(name) \
        a0 += (float)v##name[0]; a1 += (float)v##name[1]; \
        a2 += (float)v##name[2]; a3 += (float)v##name[3];

        if (dc <= 16) {
            GLD(A, 0) GLD(B, 4) GLD(C, 8) GLD(D, 12)
            GACC(A) GACC(B) GACC(C) GACC(D)
        } else {
            GLD(A, 0) GLD(B, 4) GLD(C, 8) GLD(D, 12)
            GLD(E, 16) GLD(F, 20) GLD(G, 24) GLD(H, 28)
            GACC(A) GACC(B) GACC(C) GACC(D)
            GACC(E) GACC(F) GACC(G) GACC(H)
            for (int e = 32 + g; e < dc; e += 4) {
                int s_ = __shfl(idxv, e, 64);
                bf16x4 v_ = *(const bf16x4*)(xb + (size_t)s_ * 64 + f4);
                a0 += (float)v_[0]; a1 += (float)v_[1];
                a2 += (float)v_[2]; a3 += (float)v_[3];
            }
        }
#undef GLD
#undef GACC
        a0 += __shfl_xor(a0, 16, 64); a0 += __shfl_xor(a0, 32, 64);
        a1 += __shfl_xor(a1, 16, 64); a1 += __shfl_xor(a1, 32, 64);
        a2 += __shfl_xor(a2, 16, 64); a2 += __shfl_xor(a2, 32, 64);
        a3 += __shfl_xor(a3, 16, 64); a3 += __shfl_xor(a3, 32, 64);
        float inv = 1.f / fmaxf((float)dc, 1.f);
        if (l < 16) {
            f32x4 o = {a0 * inv, a1 * inv, a2 * inv, a3 * inv};
            *(f32x4*)&sw[t * 68 + f4] = o;
        }
    }

    bf16x8 ah0, al0, ah1, al1;
    split8(&sw[f16 * 68 + k0], ah0, al0);
    split8(&sw[f16 * 68 + 32 + k0], ah1, al1);

    bf16x8 xh0 = zero8(), xl0 = zero8(), xh1 = zero8(), xl1 = zero8();
    {
        int xrow = base + f16;
        if (xrow < N_NODES) {
            split8(&x[xrow * 64 + k0], xh0, xl0);
            split8(&x[xrow * 64 + 32 + k0], xh1, xl1);
        }
    }

#pragma unroll 1
    for (int jj = 0; jj < 4; ++jj) {
        float bhr = b_hh[jj * 16 + f16], bhz = b_hh[64 + jj * 16 + f16], bhn = b_hh[128 + jj * 16 + f16];
        f32x4 ghr = {bhr, bhr, bhr, bhr}, ghz = {bhz, bhz, bhz, bhz}, ghn = {bhn, bhn, bhn, bhn};
        ghr = mm6(ghr, xh0, xh1, xl0, xl1, ph, pl, GT_WHH + jj, l);
        ghz = mm6(ghz, xh0, xh1, xl0, xl1, ph, pl, GT_WHH + 4 + jj, l);
        ghn = mm6(ghn, xh0, xh1, xl0, xl1, ph, pl, GT_WHH + 8 + jj, l);
        __builtin_amdgcn_sched_barrier(0);
        float bir = b_ih[jj * 16 + f16], biz = b_ih[64 + jj * 16 + f16], bin_ = b_ih[128 + jj * 16 + f16];
        f32x4 gir = {bir, bir, bir, bir}, giz = {biz, biz, biz, biz}, gin = {bin_, bin_, bin_, bin_};
        gir = mm6(gir, ah0, ah1, al0, al1, ph, pl, GT_WIH + jj, l);
        giz = mm6(giz, ah0, ah1, al0, al1, ph, pl, GT_WIH + 4 + jj, l);
        gin = mm6(gin, ah0, ah1, al0, al1, ph, pl, GT_WIH + 8 + jj, l);
        __builtin_amdgcn_sched_barrier(0);
#pragma unroll
        for (int rr = 0; rr < 4; ++rr) {
            int row = base + hq * 4 + rr;
            float xc = (row < N_NODES) ? x[row * 64 + jj * 16 + f16] : 0.f;
            float gr = sigm(gir[rr] + ghr[rr]);
            float gz = sigm(giz[rr] + ghz[rr]);
            float gn = tanh_(gin[rr] + gr * ghn[rr]);
            sw[(hq * 4 + rr) * 68 + jj * 16 + f16] = (1.f - gz) * gn + gz * xc;
        }
    }

    bf16x8 hh0, hl0, hh1, hl1;
    split8(&sw[f16 * 68 + k0], hh0, hl0);
    split8(&sw[f16 * 68 + 32 + k0], hh1, hl1);

#pragma unroll 1
    for (int jj = 0; jj < 4; ++jj) {
        float bi = lb_ih[jj * 16 + f16] + lb_hh[jj * 16 + f16];
        float bg = lb_ih[128 + jj * 16 + f16] + lb_hh[128 + jj * 16 + f16];
        float bo = lb_ih[192 + jj * 16 + f16] + lb_hh[192 + jj * 16 + f16];
        f32x4 ai = {bi, bi, bi, bi}, ag = {bg, bg, bg, bg}, ao = {bo, bo, bo, bo};
        ai = mm6(ai, hh0, hh1, hl0, hl1, ph, pl, GT_LSTM + jj, l);
        ag = mm6(ag, hh0, hh1, hl0, hl1, ph, pl, GT_LSTM + 4 + jj, l);
        ao = mm6(ao, hh0, hh1, hl0, hl1, ph, pl, GT_LSTM + 8 + jj, l);
        __builtin_amdgcn_sched_barrier(0);
#pragma unroll
        for (int rr = 0; rr < 4; ++rr) {
            float c = sigm(ai[rr]) * tanh_(ag[rr]);
            float ht = sigm(ao[rr]) * tanh_(c);
            sw[(hq * 4 + rr) * 68 + jj * 16 + f16] = fmaxf(ht, 0.f);
        }
    }

    bf16x8 rh0, rl0, rh1, rl1;
    split8(&sw[f16 * 68 + k0], rh0, rl0);
    split8(&sw[f16 * 68 + 32 + k0], rh1, rl1);

#pragma unroll 1
    for (int jj = 0; jj < 4; ++jj) {
        float bb = lin_b[jj * 16 + f16];
        f32x4 acc = {bb, bb, bb, bb};
        acc = mm6(acc, rh0, rh1, rl0, rl1, ph, pl, GT_LIN + jj, l);
#pragma unroll
        for (int rr = 0; rr < 4; ++rr) {
            int row = base + hq * 4 + rr;
            if (row < N_NODES) __builtin_nontemporal_store(acc[rr], &out[row * 64 + jj * 16 + f16]);
        }
    }
}

extern "C" void kernel_launch(void* const* d_in, const int* in_sizes, int n_in,
                              void* d_out, int out_size, void* d_ws, size_t ws_size,
                              hipStream_t stream) {
    const float* x    = (const float*)d_in[0];
    const int*   ei   = (const int*)d_in[1];
    const float* Wc   = (const float*)d_in[2];
    const float* gwih = (const float*)d_in[3];
    const float* gwhh = (const float*)d_in[4];
    const float* gbih = (const float*)d_in[5];
    const float* gbhh = (const float*)d_in[6];
    const float* lwih = (const float*)d_in[7];
    // d_in[8] lstm_w_hh unused (h0 = 0)
    const float* lbih = (const float*)d_in[9];
    const float* lbhh = (const float*)d_in[10];
    const float* linw = (const float*)d_in[11];
    const float* linb = (const float*)d_in[12];
    float* out = (float*)d_out;

    int*    ss   = (int*)d_ws;                              // 6.4M ints = 25.6 MB
    int*    cnt  = ss + (size_t)N_NODES * PAD_DEG;          // 100000 ints
    int*    gcur = cnt + N_NODES;                           // 8 ints (memset with cnt)
    bf16_t* ph   = (bf16_t*)(gcur + 8);                     // 40960 bf16
    bf16_t* pl   = ph + PACK_ELEMS;                         // 40960 bf16
    bf16_t* xb   = pl + PACK_ELEMS;                         // (N+1)*64 bf16 = 12.8 MB
    int*    gbuf = (int*)(xb + (size_t)(N_NODES + 1) * 64); // 8*204800 ints = 6.55 MB

    hipMemsetAsync(cnt, 0, (size_t)(N_NODES + 8) * sizeof(int), stream);

    dim3 b(256);
    k_part<<<dim3(PART_BLOCKS + CAST_BLOCKS + PACK_BLOCKS), b, 0, stream>>>(
        ei, gcur, gbuf, x, xb, Wc, gwih, gwhh, lwih, linw, ph, pl);
    k_scat<<<dim3(8 * SCAT_GROUP), b, 0, stream>>>(gbuf, gcur, cnt, ss);
    k_fused<<<dim3((N_NODES + 63) / 64), b, 0, stream>>>(
        x, xb, ss, cnt, ph, pl, gbih, gbhh, lbih, lbhh, linb, out);
}

// Round 14
// 173.185 us; speedup vs baseline: 2.8695x; 2.8695x over previous
//
#include <hip/hip_runtime.h>
#include <math.h>

#define N_NODES 100000
#define N_EDGES 1600000
#define PAD_DEG 64

typedef __bf16 bf16_t;
typedef __attribute__((ext_vector_type(8))) __bf16 bf16x8;
typedef __attribute__((ext_vector_type(4))) __bf16 bf16x4;
typedef __attribute__((ext_vector_type(4))) float f32x4;

// packed weight tile groups (each tile: 16 output cols x K=64, split hi/lo planes)
#define GT_WHH  0    // 12 tiles: gru_w_hh (192 x 64)
#define GT_WIH  12   // 12 tiles: WC = Wc @ gru_w_ih^T  (64 x 192)
#define GT_LSTM 24   // 12 tiles: lstm_w_ih rows i,g,o (192 x 64)
#define GT_LIN  36   // 4 tiles:  lin_w (64 x 64)
#define N_GT    40
#define PACK_ELEMS (N_GT * 1024)
#define CAST_BLOCKS ((N_NODES * 16 + 16 + 255) / 256)   // 6251
#define PACK_BLOCKS ((PACK_ELEMS + 255) / 256)          // 160

// dst-range-partitioned placement: 8 ranges (one per XCD-L2), PLACE_GROUP blocks each
#define NODES_PER_RANGE 12500
#define PLACE_GROUP 304
#define PLACE_BLOCKS (8 * PLACE_GROUP)

__device__ __forceinline__ float sigm(float v) { return 1.f / (1.f + __expf(-v)); }
__device__ __forceinline__ float tanh_(float v) { return 2.f * sigm(2.f * v) - 1.f; }

__device__ __forceinline__ void split8(const float* __restrict__ p, bf16x8& hi, bf16x8& lo) {
    f32x4 a = *(const f32x4*)p;
    f32x4 b = *(const f32x4*)(p + 4);
#pragma unroll
    for (int i = 0; i < 4; ++i) {
        float v = a[i];
        __bf16 h = (__bf16)v;
        hi[i] = h;
        lo[i] = (__bf16)(v - (float)h);
        v = b[i];
        h = (__bf16)v;
        hi[4 + i] = h;
        lo[4 + i] = (__bf16)(v - (float)h);
    }
}

// acc += A(16x64) * B_tile(64x16) using split-bf16 (hi*hi + lo*hi + hi*lo)
__device__ __forceinline__ f32x4 mm6(f32x4 acc, bf16x8 ah0, bf16x8 ah1, bf16x8 al0, bf16x8 al1,
                                     const bf16_t* __restrict__ ph, const bf16_t* __restrict__ pl,
                                     int gt, int l) {
    const bf16x8 bh0 = *(const bf16x8*)(ph + (gt * 2 + 0) * 512 + l * 8);
    const bf16x8 bh1 = *(const bf16x8*)(ph + (gt * 2 + 1) * 512 + l * 8);
    const bf16x8 bl0 = *(const bf16x8*)(pl + (gt * 2 + 0) * 512 + l * 8);
    const bf16x8 bl1 = *(const bf16x8*)(pl + (gt * 2 + 1) * 512 + l * 8);
    acc = __builtin_amdgcn_mfma_f32_16x16x32_bf16(ah0, bh0, acc, 0, 0, 0);
    acc = __builtin_amdgcn_mfma_f32_16x16x32_bf16(ah1, bh1, acc, 0, 0, 0);
    acc = __builtin_amdgcn_mfma_f32_16x16x32_bf16(al0, bh0, acc, 0, 0, 0);
    acc = __builtin_amdgcn_mfma_f32_16x16x32_bf16(al1, bh1, acc, 0, 0, 0);
    acc = __builtin_amdgcn_mfma_f32_16x16x32_bf16(ah0, bl0, acc, 0, 0, 0);
    acc = __builtin_amdgcn_mfma_f32_16x16x32_bf16(ah1, bl1, acc, 0, 0, 0);
    return acc;
}

// ---------------- prologue: place edges (long pole, first), cast x->bf16, pack weights ----------------
__global__ __launch_bounds__(256) void k_pre(const float* __restrict__ x, bf16_t* __restrict__ xb,
                                             const float* __restrict__ Wc,
                                             const float* __restrict__ wih,
                                             const float* __restrict__ whh,
                                             const float* __restrict__ lw,
                                             const float* __restrict__ lin,
                                             bf16_t* __restrict__ ph, bf16_t* __restrict__ pl,
                                             const int* __restrict__ ei,
                                             int* __restrict__ cnt, int* __restrict__ ss) {
    int b = blockIdx.x;
    if (b < PLACE_BLOCKS) {
        // placement: range r handled by blocks with (b & 7) == r -> same XCD under %8 round-robin,
        // so the 3.2 MB ss slice of range r stays mostly in one XCD L2.
        int r = b & 7, gi = b >> 3;
        int lo = r * NODES_PER_RANGE;
        int hi = lo + NODES_PER_RANGE;   // 8*12500 == N_NODES exactly
        for (int e = gi * 256 + threadIdx.x; e < N_EDGES; e += PLACE_GROUP * 256) {
            int d = ei[N_EDGES + e];
            if (d >= lo && d < hi) {
                int s = ei[e];
                int p = atomicAdd(&cnt[d], 1);
                if (p < PAD_DEG) ss[d * PAD_DEG + p] = s;
            }
        }
        return;
    }
    b -= PLACE_BLOCKS;
    if (b < CAST_BLOCKS) {
        int t = b * 256 + threadIdx.x;
        if (t < N_NODES * 16) {
            f32x4 v = *(const f32x4*)(x + (size_t)t * 4);
            bf16x4 o;
#pragma unroll
            for (int i = 0; i < 4; ++i) o[i] = (__bf16)v[i];
            *(bf16x4*)(xb + (size_t)t * 4) = o;
        } else if (t < N_NODES * 16 + 16) {
            bf16x4 o;
#pragma unroll
            for (int i = 0; i < 4; ++i) o[i] = (__bf16)0.f;
            *(bf16x4*)(xb + (size_t)t * 4) = o;
        }
        return;
    }
    b -= CAST_BLOCKS;
    int t = b * 256 + threadIdx.x;
    if (t >= PACK_ELEMS) return;
    int i = t & 7, lane = (t >> 3) & 63, kk = (t >> 9) & 1, gt = t >> 10;
    int f = lane & 15;
    int k = kk * 32 + (lane >> 4) * 8 + i;
    float v;
    if (gt < 12) {
        v = whh[(gt * 16 + f) * 64 + k];
    } else if (gt < 24) {
        int j = (gt - 12) * 16 + f;
        float acc = 0.f;
        for (int c = 0; c < 64; ++c) acc += Wc[k * 64 + c] * wih[j * 64 + c];
        v = acc;
    } else if (gt < 36) {
        int jg = (gt - 24) * 16 + f;
        int row = (jg < 64) ? jg : jg + 64;  // i: 0..63, g: 128..191, o: 192..255
        v = lw[row * 64 + k];
    } else {
        v = lin[((gt - 36) * 16 + f) * 64 + k];
    }
    __bf16 h = (__bf16)v;
    ph[t] = h;
    pl[t] = (__bf16)(v - (float)h);
}

// ---------------- fused gather-mean -> (agg@WC, x@Whh) GRU -> LSTM -> ReLU+Linear ----------------
__global__ __launch_bounds__(256) void k_fused(
    const float* __restrict__ x, const bf16_t* __restrict__ xb,
    const int* __restrict__ ss, const int* __restrict__ cnt,
    const bf16_t* __restrict__ ph, const bf16_t* __restrict__ pl,
    const float* __restrict__ b_ih, const float* __restrict__ b_hh,
    const float* __restrict__ lb_ih, const float* __restrict__ lb_hh,
    const float* __restrict__ lin_b, float* __restrict__ out) {
    __shared__ float sc[4 * 16 * 68];  // agg staging, per-wave slices
    __shared__ float xs[4 * 16 * 68];  // x staging (read x from HBM exactly once)
    int tid = threadIdx.x, w = tid >> 6, l = tid & 63;
    int base = blockIdx.x * 64 + w * 16;
    float* sw = &sc[w * 16 * 68];
    float* xw = &xs[w * 16 * 68];
    int f16 = l & 15, k0 = (l >> 4) * 8, hq = l >> 4;

    // ---- stage x into LDS (coalesced f32x4, issued before the gather to hide) ----
    {
        int rl = (l >> 4) * 4;          // row group base 0/4/8/12
        int c4 = (l & 15) * 4;          // feature quad
#pragma unroll
        for (int rr2 = 0; rr2 < 4; ++rr2) {
            int row = base + rl + rr2;
            f32x4 v = {0.f, 0.f, 0.f, 0.f};
            if (row < N_NODES) v = *(const f32x4*)(x + (size_t)row * 64 + c4);
            *(f32x4*)&xw[(rl + rr2) * 68 + c4] = v;
        }
    }

    // ---- gather-mean of xb: 16 lanes/edge x 8B, static dc-bucketed batches ----
    int g = l >> 4;          // edge group 0..3
    int f4 = (l & 15) * 4;   // feature quad
    int dcl = 0;
    if (l < 16 && base + l < N_NODES) dcl = cnt[base + l];
    if (dcl > PAD_DEG) dcl = PAD_DEG;

    int idxq = 0;
    if (base < N_NODES) idxq = ss[(size_t)base * PAD_DEG + l];

#pragma unroll 1
    for (int t = 0; t < 16; ++t) {
        int dc = __shfl(dcl, t, 64);
        int idxv = (l < dc) ? idxq : N_NODES;   // OOB slots -> dummy zero row
        if (t < 15 && base + t + 1 < N_NODES) idxq = ss[(size_t)(base + t + 1) * PAD_DEG + l];
        float a0 = 0.f, a1 = 0.f, a2 = 0.f, a3 = 0.f;

#define GLD(name, sb) \
        int s##name = __shfl(idxv, (sb) + g, 64); \
        bf16x4 v##name = *(const bf16x4*)(xb + (size_t)s##name * 64 + f4);
#define GACC(name) \
        a0 += (float)v##name[0]; a1 += (float)v##name[1]; \
        a2 += (float)v##name[2]; a3 += (float)v##name[3];

        if (dc <= 16) {          // 4 loads in flight (57% of rows)
            GLD(A, 0) GLD(B, 4) GLD(C, 8) GLD(D, 12)
            GACC(A) GACC(B) GACC(C) GACC(D)
        } else {                 // 8 loads in flight (43% of rows)
            GLD(A, 0) GLD(B, 4) GLD(C, 8) GLD(D, 12)
            GLD(E, 16) GLD(F, 20) GLD(G, 24) GLD(H, 28)
            GACC(A) GACC(B) GACC(C) GACC(D)
            GACC(E) GACC(F) GACC(G) GACC(H)
            // rare tail dc > 32 (P ~ 1e-4)
            for (int e = 32 + g; e < dc; e += 4) {
                int s_ = __shfl(idxv, e, 64);
                bf16x4 v_ = *(const bf16x4*)(xb + (size_t)s_ * 64 + f4);
                a0 += (float)v_[0]; a1 += (float)v_[1];
                a2 += (float)v_[2]; a3 += (float)v_[3];
            }
        }
#undef GLD
#undef GACC
        // reduce over 4 edge-groups: lanes {f, f+16, f+32, f+48}
        a0 += __shfl_xor(a0, 16, 64); a0 += __shfl_xor(a0, 32, 64);
        a1 += __shfl_xor(a1, 16, 64); a1 += __shfl_xor(a1, 32, 64);
        a2 += __shfl_xor(a2, 16, 64); a2 += __shfl_xor(a2, 32, 64);
        a3 += __shfl_xor(a3, 16, 64); a3 += __shfl_xor(a3, 32, 64);
        float inv = 1.f / fmaxf((float)dc, 1.f);
        if (l < 16) {
            f32x4 o = {a0 * inv, a1 * inv, a2 * inv, a3 * inv};
            *(f32x4*)&sw[t * 68 + f4] = o;
        }
    }

    // ---- A-fragments: agg and x from LDS ----
    bf16x8 ah0, al0, ah1, al1;
    split8(&sw[f16 * 68 + k0], ah0, al0);
    split8(&sw[f16 * 68 + 32 + k0], ah1, al1);
    bf16x8 xh0, xl0, xh1, xl1;
    split8(&xw[f16 * 68 + k0], xh0, xl0);
    split8(&xw[f16 * 68 + 32 + k0], xh1, xl1);

    // ---- GRU: gh = x@whh^T + bhh ; gi = agg@WC + bih ; gates -> direct LDS store ----
#pragma unroll 1
    for (int jj = 0; jj < 4; ++jj) {
        float bhr = b_hh[jj * 16 + f16], bhz = b_hh[64 + jj * 16 + f16], bhn = b_hh[128 + jj * 16 + f16];
        f32x4 ghr = {bhr, bhr, bhr, bhr}, ghz = {bhz, bhz, bhz, bhz}, ghn = {bhn, bhn, bhn, bhn};
        ghr = mm6(ghr, xh0, xh1, xl0, xl1, ph, pl, GT_WHH + jj, l);
        ghz = mm6(ghz, xh0, xh1, xl0, xl1, ph, pl, GT_WHH + 4 + jj, l);
        ghn = mm6(ghn, xh0, xh1, xl0, xl1, ph, pl, GT_WHH + 8 + jj, l);
        __builtin_amdgcn_sched_barrier(0);
        float bir = b_ih[jj * 16 + f16], biz = b_ih[64 + jj * 16 + f16], bin_ = b_ih[128 + jj * 16 + f16];
        f32x4 gir = {bir, bir, bir, bir}, giz = {biz, biz, biz, biz}, gin = {bin_, bin_, bin_, bin_};
        gir = mm6(gir, ah0, ah1, al0, al1, ph, pl, GT_WIH + jj, l);
        giz = mm6(giz, ah0, ah1, al0, al1, ph, pl, GT_WIH + 4 + jj, l);
        gin = mm6(gin, ah0, ah1, al0, al1, ph, pl, GT_WIH + 8 + jj, l);
        __builtin_amdgcn_sched_barrier(0);
#pragma unroll
        for (int rr = 0; rr < 4; ++rr) {
            float xc = xw[(hq * 4 + rr) * 68 + jj * 16 + f16];
            float gr = sigm(gir[rr] + ghr[rr]);
            float gz = sigm(giz[rr] + ghz[rr]);
            float gn = tanh_(gin[rr] + gr * ghn[rr]);
            sw[(hq * 4 + rr) * 68 + jj * 16 + f16] = (1.f - gz) * gn + gz * xc;
        }
    }

    // h A-frags from LDS
    bf16x8 hh0, hl0, hh1, hl1;
    split8(&sw[f16 * 68 + k0], hh0, hl0);
    split8(&sw[f16 * 68 + 32 + k0], hh1, hl1);

    // ---- LSTM gates i,g,o (f dead: c0 = 0) -> relu -> direct LDS store ----
#pragma unroll 1
    for (int jj = 0; jj < 4; ++jj) {
        float bi = lb_ih[jj * 16 + f16] + lb_hh[jj * 16 + f16];
        float bg = lb_ih[128 + jj * 16 + f16] + lb_hh[128 + jj * 16 + f16];
        float bo = lb_ih[192 + jj * 16 + f16] + lb_hh[192 + jj * 16 + f16];
        f32x4 ai = {bi, bi, bi, bi}, ag = {bg, bg, bg, bg}, ao = {bo, bo, bo, bo};
        ai = mm6(ai, hh0, hh1, hl0, hl1, ph, pl, GT_LSTM + jj, l);
        ag = mm6(ag, hh0, hh1, hl0, hl1, ph, pl, GT_LSTM + 4 + jj, l);
        ao = mm6(ao, hh0, hh1, hl0, hl1, ph, pl, GT_LSTM + 8 + jj, l);
        __builtin_amdgcn_sched_barrier(0);
#pragma unroll
        for (int rr = 0; rr < 4; ++rr) {
            float c = sigm(ai[rr]) * tanh_(ag[rr]);
            float ht = sigm(ao[rr]) * tanh_(c);
            sw[(hq * 4 + rr) * 68 + jj * 16 + f16] = fmaxf(ht, 0.f);
        }
    }

    // relu A-frags from LDS
    bf16x8 rh0, rl0, rh1, rl1;
    split8(&sw[f16 * 68 + k0], rh0, rl0);
    split8(&sw[f16 * 68 + 32 + k0], rh1, rl1);

    // ---- out = relu @ lin^T + b (nt stores: coalesced full lines, never re-read) ----
#pragma unroll 1
    for (int jj = 0; jj < 4; ++jj) {
        float bb = lin_b[jj * 16 + f16];
        f32x4 acc = {bb, bb, bb, bb};
        acc = mm6(acc, rh0, rh1, rl0, rl1, ph, pl, GT_LIN + jj, l);
#pragma unroll
        for (int rr = 0; rr < 4; ++rr) {
            int row = base + hq * 4 + rr;
            if (row < N_NODES) __builtin_nontemporal_store(acc[rr], &out[row * 64 + jj * 16 + f16]);
        }
    }
}

extern "C" void kernel_launch(void* const* d_in, const int* in_sizes, int n_in,
                              void* d_out, int out_size, void* d_ws, size_t ws_size,
                              hipStream_t stream) {
    const float* x    = (const float*)d_in[0];
    const int*   ei   = (const int*)d_in[1];
    const float* Wc   = (const float*)d_in[2];
    const float* gwih = (const float*)d_in[3];
    const float* gwhh = (const float*)d_in[4];
    const float* gbih = (const float*)d_in[5];
    const float* gbhh = (const float*)d_in[6];
    const float* lwih = (const float*)d_in[7];
    // d_in[8] lstm_w_hh unused (h0 = 0)
    const float* lbih = (const float*)d_in[9];
    const float* lbhh = (const float*)d_in[10];
    const float* linw = (const float*)d_in[11];
    const float* linb = (const float*)d_in[12];
    float* out = (float*)d_out;

    int*    ss  = (int*)d_ws;                               // 100000*64 ints = 25.6 MB
    int*    cnt = ss + (size_t)N_NODES * PAD_DEG;           // 100000 ints
    bf16_t* ph  = (bf16_t*)(cnt + N_NODES);                 // 40960 bf16
    bf16_t* pl  = ph + PACK_ELEMS;                          // 40960 bf16
    bf16_t* xb  = pl + PACK_ELEMS;                          // (N_NODES+1)*64 bf16

    hipMemsetAsync(cnt, 0, (size_t)N_NODES * sizeof(int), stream);

    dim3 b(256);
    k_pre<<<dim3(PLACE_BLOCKS + CAST_BLOCKS + PACK_BLOCKS), b, 0, stream>>>(
        x, xb, Wc, gwih, gwhh, lwih, linw, ph, pl, ei, cnt, ss);
    k_fused<<<dim3((N_NODES + 63) / 64), b, 0, stream>>>(
        x, xb, ss, cnt, ph, pl, gbih, gbhh, lbih, lbhh, linb, out);
}